// Round 23
// baseline (2569.113 us; speedup 1.0000x reference)
//
#include <hip/hip_runtime.h>
#include <math.h>

typedef unsigned short u16;
typedef _Float16 h16;
typedef _Float16 f16x8 __attribute__((ext_vector_type(8)));
typedef float f32x4 __attribute__((ext_vector_type(4)));

__device__ __forceinline__ float sigm(float x) { return 1.f / (1.f + expf(-x)); }

// ---------------- Prologue kernels ----------------

// Pack W = [Wx;Wh] (1024 x 2048 f32) into per-colblock f16 hi/lo MFMA b-frag
// streams. Layout: [j 0..64)[ks 0..32)[cf 0..2)[l 0..64)[e 0..8)
// element = W[k = ks*32 + (l>>4)*8 + e][acol], acol = (c32>>3)*512 + j*8 + (c32&7),
// c32 = cf*16 + (l&15).  lo scaled by 2^12 (exact) to stay in fp16 normal range.
__global__ void k_pack_w(const float* __restrict__ Wx, const float* __restrict__ Wh,
                         h16* __restrict__ WhiS, h16* __restrict__ WloS) {
  unsigned idx = blockIdx.x * 256 + threadIdx.x;   // 0..2097151
  unsigned e = idx & 7, l = (idx >> 3) & 63, cf = (idx >> 9) & 1;
  unsigned t2 = idx >> 10;                          // j*32 + ks
  unsigned j = t2 >> 5, ks = t2 & 31;
  unsigned k = ks * 32 + ((l >> 4) << 3) + e;       // 0..1023
  unsigned c32 = cf * 16 + (l & 15);
  unsigned acol = (c32 >> 3) * 512 + j * 8 + (c32 & 7);
  float v = (k < 512) ? Wx[(size_t)k * 2048 + acol]
                      : Wh[(size_t)(k - 512) * 2048 + acol];
  h16 hi = (h16)v;
  WhiS[idx] = hi;
  WloS[idx] = (h16)((v - (float)hi) * 4096.f);
}

// Af -> a-frag hi/lo streams for k_m: [n][ksg 16][l 64][e 8],
// element = A[n][k = ksg*32+(l>>4)*8+e][p = l&15].
__global__ void k_af_pack(const float* __restrict__ Af, h16* __restrict__ afhi,
                          h16* __restrict__ aflo) {
  unsigned idx = blockIdx.x * 256 + threadIdx.x;   // 0..2097151
  unsigned e = idx & 7, l = (idx >> 3) & 63, ksg = (idx >> 9) & 15, n = idx >> 13;
  unsigned k = ksg * 32 + ((l >> 4) << 3) + e;
  float v = Af[(size_t)n * 8192 + k * 16 + (l & 15)];
  h16 hi = (h16)v;
  afhi[idx] = hi;
  aflo[idx] = (h16)((v - (float)hi) * 4096.f);
}

// Wattn -> b-frag hi/lo streams for k_m: [cg 128][ksg 16][l 64][e 8],
// element = Wat[k = ksg*32+(l>>4)*8+e][col = cg*16 + (l&15)].
__global__ void k_wat_pack(const float* __restrict__ Wat, h16* __restrict__ wathi,
                           h16* __restrict__ watlo) {
  unsigned idx = blockIdx.x * 256 + threadIdx.x;   // 0..1048575
  unsigned e = idx & 7, l = (idx >> 3) & 63, ksg = (idx >> 9) & 15, cg = idx >> 13;
  unsigned k = ksg * 32 + ((l >> 4) << 3) + e;
  float v = Wat[(size_t)k * 2048 + cg * 16 + (l & 15)];
  h16 hi = (h16)v;
  wathi[idx] = hi;
  watlo[idx] = (h16)((v - (float)hi) * 4096.f);
}

// M2[n][col][p] = sum_k A[n][k][p]*Wat[k][col], f16 hi/lo 3-pass MFMA from
// prepacked frag streams. Grid (32 ct, 32 ng) x 256 thr: block = 64 cols x 8 n.
// acc2 split into two accumulators (a/b) to break the per-i serial MFMA chain
// (R21: 83 -> 51 us, 1.4 TB/s).
__global__ __launch_bounds__(256) void k_m(const h16* __restrict__ afhi,
                                           const h16* __restrict__ aflo,
                                           const h16* __restrict__ wathi,
                                           const h16* __restrict__ watlo,
                                           float* __restrict__ M2) {
  const int tid = threadIdx.x;
  const int ct = blockIdx.x, ng = blockIdx.y;
  const int l = tid & 63, w = tid >> 6;
  const int cg = ct * 4 + w;
  const int col = cg * 16 + (l & 15);
  const int lq = l >> 4;
  f32x4 acc1[8], acc2a[8], acc2b[8];
#pragma unroll
  for (int i = 0; i < 8; ++i) {
    acc1[i] = (f32x4){0.f, 0.f, 0.f, 0.f};
    acc2a[i] = (f32x4){0.f, 0.f, 0.f, 0.f};
    acc2b[i] = (f32x4){0.f, 0.f, 0.f, 0.f};
  }
  for (int ksg = 0; ksg < 16; ++ksg) {
    const size_t boff = (((size_t)cg * 16 + ksg) * 64 + l) * 8;
    const f16x8 bh = *(const f16x8*)(wathi + boff);
    const f16x8 bl = *(const f16x8*)(watlo + boff);
#pragma unroll
    for (int i = 0; i < 8; ++i) {
      const size_t aoff = (((size_t)(ng * 8 + i) * 16 + ksg) * 64 + l) * 8;
      const f16x8 ah = *(const f16x8*)(afhi + aoff);
      const f16x8 al = *(const f16x8*)(aflo + aoff);
      acc1[i]  = __builtin_amdgcn_mfma_f32_16x16x32_f16(ah, bh, acc1[i], 0, 0, 0);
      acc2a[i] = __builtin_amdgcn_mfma_f32_16x16x32_f16(al, bh, acc2a[i], 0, 0, 0);
      acc2b[i] = __builtin_amdgcn_mfma_f32_16x16x32_f16(ah, bl, acc2b[i], 0, 0, 0);
    }
  }
#pragma unroll
  for (int i = 0; i < 8; ++i) {
    float4 o;
    o.x = acc1[i][0] + (acc2a[i][0] + acc2b[i][0]) * (1.f / 4096.f);
    o.y = acc1[i][1] + (acc2a[i][1] + acc2b[i][1]) * (1.f / 4096.f);
    o.z = acc1[i][2] + (acc2a[i][2] + acc2b[i][2]) * (1.f / 4096.f);
    o.w = acc1[i][3] + (acc2a[i][3] + acc2b[i][3]) * (1.f / 4096.f);
    *(float4*)(M2 + ((size_t)(ng * 8 + i) * 2048 + col) * 16 + lq * 4) = o;
  }
}

// x (f32) -> xfhi/xflo in MFMA-FRAGMENT order: [t][g 8][ksg 16][rt 2][l][e],
// element = x[n = g*32+rt*16+(l&15)][t][k = ksg*32+(l>>4)*8+e].
__global__ void k_xsplit(const float* __restrict__ x, h16* __restrict__ xfhi,
                         h16* __restrict__ xflo) {
  unsigned tg = blockIdx.x * 256 + threadIdx.x;   // 0..2097151
  unsigned l = tg & 63, rt = (tg >> 6) & 1, ksg = (tg >> 7) & 15;
  unsigned g = (tg >> 11) & 7, t = tg >> 14;
  int n = g * 32 + rt * 16 + (l & 15);
  int k0 = ksg * 32 + (l >> 4) * 8;
  const float* xp = x + ((size_t)n * 128 + t) * 512 + k0;
  f32x4 v0 = *(const f32x4*)xp, v1 = *(const f32x4*)(xp + 4);
  float vv[8] = {v0[0], v0[1], v0[2], v0[3], v1[0], v1[1], v1[2], v1[3]};
  union { h16 h[8]; uint4 u; } a, b;
#pragma unroll
  for (int e = 0; e < 8; ++e) {
    h16 hh = (h16)vv[e];
    a.h[e] = hh;
    b.h[e] = (h16)((vv[e] - (float)hh) * 4096.f);
  }
  *(uint4*)(xfhi + (size_t)tg * 8) = a.u;
  *(uint4*)(xflo + (size_t)tg * 8) = b.u;
}

// h0 = c0 = mean_p A[n][k][p]; seeds cst, h-FRAGMENT buffers (buf 0) and the
// step-0 score partials sb0[n][j][p]. 256 blocks (n) x 512 threads (k).
// h-frag addr: [g][hksg=k>>5][rt=(n>>4)&1][lfrag=(n&15)|(((k>>3)&3)<<4)][e=k&7]
__global__ __launch_bounds__(512) void k_init(const float* __restrict__ Af,
                                              h16* __restrict__ hfhi,
                                              h16* __restrict__ hflo,
                                              float* __restrict__ cst,
                                              float* __restrict__ sb0) {
  const int n = blockIdx.x, k = threadIdx.x;
  float Areg[16];
  const f32x4* A4 = (const f32x4*)(Af + (size_t)n * 8192 + k * 16);
#pragma unroll
  for (int q4 = 0; q4 < 4; ++q4) {
    f32x4 v = A4[q4];
#pragma unroll
    for (int e = 0; e < 4; ++e) Areg[q4 * 4 + e] = v[e];
  }
  float s = 0.f;
#pragma unroll
  for (int p = 0; p < 16; ++p) s += Areg[p];
  s *= 0.0625f;
  cst[n * 512 + k] = s;
  h16 hh = (h16)s;
  const int g = n >> 5;
  const int hoff = ((((g * 16 + (k >> 5)) * 2 + ((n >> 4) & 1)) * 64 +
                     ((n & 15) | (((k >> 3) & 3) << 4))) * 8) + (k & 7);
  hfhi[hoff] = hh;
  hflo[hoff] = (h16)((s - (float)hh) * 4096.f);
  float ps[16];
#pragma unroll
  for (int p = 0; p < 16; ++p) ps[p] = s * Areg[p];
#pragma unroll
  for (int m = 1; m <= 4; m <<= 1)
#pragma unroll
    for (int p = 0; p < 16; ++p) ps[p] += __shfl_xor(ps[p], m);
  if ((k & 7) == 0) {
    float* o = sb0 + ((size_t)n * 64 + (k >> 3)) * 16;
#pragma unroll
    for (int p = 0; p < 16; ++p) o[p] = ps[p];
  }
}

// ------------- Fused per-step kernel: softmax + GEMM + cell + next-scores -----
// 512 blocks x 512 threads. R23 change: __launch_bounds__(512, 6) -> 3 blocks/CU
// (24 waves/CU, 75% occupancy) to cut latency exposure (R22 analysis: k_step is
// latency-bound at 16 waves/CU; neither HBM- nor MFMA-bound). LDS 3x31.6=95 KB.
// Block: g = bid>>6 (rows n0=g*32), j = (bid&7)*8 + ((bid>>3)&7) (XCD-pinned W).
template<bool XPRE>
__global__ __launch_bounds__(512, 6) void k_step(
    const float* __restrict__ bv, const float* __restrict__ Af,
    const float* __restrict__ x, const h16* __restrict__ xfhi, const h16* __restrict__ xflo,
    const h16* __restrict__ WhiS, const h16* __restrict__ WloS,
    const float* __restrict__ Mws,
    const float* __restrict__ sbR, float* __restrict__ sbW,
    h16* __restrict__ hfhi, h16* __restrict__ hflo,
    float* __restrict__ cst, float* __restrict__ out, int t) {
  __shared__ float P[7 * 1056];   // 7 slots of [32 rows][33] : 29568 B
  __shared__ float wsh[32][17];   // softmax weights for this row group (+1 pad)

  const int tid = threadIdx.x;
  const int l = tid & 63, wv = tid >> 6;
  const int bid = blockIdx.x;
  const int g = bid >> 6;                          // 0..7
  const int j = (bid & 7) * 8 + ((bid >> 3) & 7);  // 0..63
  const int n0 = g * 32;

  // ---- [S] softmax: s[n][p] = sum_j sbR[n][j][p]; w = softmax(s/sqrt(512)) ----
  {
    const int nS = tid >> 4, pS = tid & 15;
    const float* sr = sbR + ((size_t)(n0 + nS) * 64) * 16 + pS;
    float s = 0.f;
#pragma unroll 8
    for (int jj = 0; jj < 64; ++jj) s += sr[jj * 16];
    s *= 0.04419417382415922f;   // 1/sqrt(512)
    float m = s;
#pragma unroll
    for (int o = 8; o >= 1; o >>= 1) m = fmaxf(m, __shfl_xor(m, o, 16));
    float e = __expf(s - m);
    float se = e;
#pragma unroll
    for (int o = 8; o >= 1; o >>= 1) se += __shfl_xor(se, o, 16);
    wsh[nS][pS] = e / se;   // ordered before cell use by the tree's syncthreads
  }

  const h16* whiJ = WhiS + (size_t)j * 32768;
  const h16* wloJ = WloS + (size_t)j * 32768;

  const int rC = tid >> 3, qC = tid & 7;   // cell mapping (tid < 256 only)
  const int colC = j * 8 + qC;
  const float b_i = bv[colC], b_f = bv[512 + colC], b_o = bv[1024 + colC],
              b_g = bv[1536 + colC];

  const int rb = t & 1, wb = rb ^ 1;
  const h16* hfhiR = hfhi + (size_t)rb * 131072;
  const h16* hfloR = hflo + (size_t)rb * 131072;

  f32x4 acc1[2][2], acc2[2][2];
#pragma unroll
  for (int rt = 0; rt < 2; ++rt)
#pragma unroll
    for (int cf = 0; cf < 2; ++cf) {
      acc1[rt][cf] = (f32x4){0.f, 0.f, 0.f, 0.f};
      acc2[rt][cf] = (f32x4){0.f, 0.f, 0.f, 0.f};
    }

  auto kstep = [&](int ksg) {
    const f16x8 bh0 = *(const f16x8*)(whiJ + ((size_t)(ksg * 2 + 0) * 64 + l) * 8);
    const f16x8 bh1 = *(const f16x8*)(whiJ + ((size_t)(ksg * 2 + 1) * 64 + l) * 8);
    const f16x8 bl0 = *(const f16x8*)(wloJ + ((size_t)(ksg * 2 + 0) * 64 + l) * 8);
    const f16x8 bl1 = *(const f16x8*)(wloJ + ((size_t)(ksg * 2 + 1) * 64 + l) * 8);
    f16x8 Ah[2], Al[2];
    if (ksg < 16) {
      if (XPRE) {
#pragma unroll
        for (int rt = 0; rt < 2; ++rt) {
          const size_t base = ((((size_t)t * 8 + g) * 16 + ksg) * 2 + rt) * 512 + l * 8;
          Ah[rt] = *(const f16x8*)(xfhi + base);
          Al[rt] = *(const f16x8*)(xflo + base);
        }
      } else {
#pragma unroll
        for (int rt = 0; rt < 2; ++rt) {
          const int n_x = g * 32 + rt * 16 + (l & 15);
          const int k_x = ksg * 32 + (l >> 4) * 8;
          const float* xp = x + ((size_t)n_x * 128 + t) * 512 + k_x;
          f32x4 v0 = *(const f32x4*)xp, v1 = *(const f32x4*)(xp + 4);
          float vv[8] = {v0[0], v0[1], v0[2], v0[3], v1[0], v1[1], v1[2], v1[3]};
#pragma unroll
          for (int e = 0; e < 8; ++e) {
            h16 hh = (h16)vv[e];
            Ah[rt][e] = hh;
            Al[rt][e] = (h16)((vv[e] - (float)hh) * 4096.f);
          }
        }
      }
    } else {
#pragma unroll
      for (int rt = 0; rt < 2; ++rt) {
        const size_t base = (((size_t)(g * 16 + (ksg - 16)) * 2 + rt) * 64 + l) * 8;
        Ah[rt] = *(const f16x8*)(hfhiR + base);
        Al[rt] = *(const f16x8*)(hfloR + base);
      }
    }
#pragma unroll
    for (int rt = 0; rt < 2; ++rt) {
      acc1[rt][0] = __builtin_amdgcn_mfma_f32_16x16x32_f16(Ah[rt], bh0, acc1[rt][0], 0, 0, 0);
      acc1[rt][1] = __builtin_amdgcn_mfma_f32_16x16x32_f16(Ah[rt], bh1, acc1[rt][1], 0, 0, 0);
      acc2[rt][0] = __builtin_amdgcn_mfma_f32_16x16x32_f16(Al[rt], bh0, acc2[rt][0], 0, 0, 0);
      acc2[rt][1] = __builtin_amdgcn_mfma_f32_16x16x32_f16(Al[rt], bh1, acc2[rt][1], 0, 0, 0);
      acc2[rt][0] = __builtin_amdgcn_mfma_f32_16x16x32_f16(Ah[rt], bl0, acc2[rt][0], 0, 0, 0);
      acc2[rt][1] = __builtin_amdgcn_mfma_f32_16x16x32_f16(Ah[rt], bl1, acc2[rt][1], 0, 0, 0);
    }
  };

  // ---- [G] K coverage: ksg = wv + 8i, i = 0..3 (x: 0..15, h: 16..31) ----
#pragma unroll
  for (int i = 0; i < 4; ++i) kstep(wv + 8 * i);

  // combine hi + 2^-12 * lo-cross
  float accf[2][2][4];
#pragma unroll
  for (int rt = 0; rt < 2; ++rt)
#pragma unroll
    for (int cf = 0; cf < 2; ++cf)
#pragma unroll
      for (int rg = 0; rg < 4; ++rg)
        accf[rt][cf][rg] = acc1[rt][cf][rg] + acc2[rt][cf][rg] * (1.f / 4096.f);

  auto publish = [&](int slot) {
#pragma unroll
    for (int rt = 0; rt < 2; ++rt)
#pragma unroll
      for (int cf = 0; cf < 2; ++cf)
#pragma unroll
        for (int rg = 0; rg < 4; ++rg)
          P[slot * 1056 + (rt * 16 + (l >> 4) * 4 + rg) * 33 + cf * 16 + (l & 15)] =
              accf[rt][cf][rg];
  };
  auto addin = [&](int slot) {
#pragma unroll
    for (int rt = 0; rt < 2; ++rt)
#pragma unroll
      for (int cf = 0; cf < 2; ++cf)
#pragma unroll
        for (int rg = 0; rg < 4; ++rg)
          accf[rt][cf][rg] +=
              P[slot * 1056 + (rt * 16 + (l >> 4) * 4 + rg) * 33 + cf * 16 + (l & 15)];
  };

  // 8-wave reduction tree: 8 -> 4 -> 2 -> 1 copies, then final publish to slot 0
  if (wv >= 4) publish(wv - 4);
  __syncthreads();
  if (wv < 4) addin(wv);
  if (wv == 2) publish(4);
  if (wv == 3) publish(5);
  __syncthreads();
  if (wv == 0) addin(4);
  if (wv == 1) { addin(5); publish(6); }
  __syncthreads();
  if (wv == 0) { addin(6); publish(0); }
  __syncthreads();

  // ---- [C] gates + w@M + state update + next-step score partials ----
  if (tid < 256) {
    const float* Mr = Mws + ((size_t)(n0 + rC) * 2048 + colC) * 16;
    float am[4];
#pragma unroll
    for (int f = 0; f < 4; ++f) {
      const float* mp = Mr + (size_t)f * 8192;   // gate offset: 512 cols * 16 p
      float s = 0.f;
#pragma unroll
      for (int p = 0; p < 16; ++p) s += wsh[rC][p] * mp[p];
      am[f] = s;
    }
    float ai = P[rC * 33 + qC] + am[0] + b_i;
    float af_ = P[rC * 33 + 8 + qC] + am[1] + b_f;
    float ao = P[rC * 33 + 16 + qC] + am[2] + b_o;
    float ag = P[rC * 33 + 24 + qC] + am[3] + b_g;
    float ig = sigm(ai), fg = sigm(af_), og = sigm(ao), gg = tanhf(ag);
    const size_t cix = (size_t)(n0 + rC) * 512 + colC;
    float c = cst[cix];
    float cn = fg * c + ig * gg;
    cst[cix] = cn;
    float hn = og * tanhf(cn);
    h16 hh = (h16)hn;
    // h-fragment write: k_h = colC; hksg = j>>2, lq = j&3, e = qC
    const int hoff = ((((g * 16 + (j >> 2)) * 2 + (rC >> 4)) * 64 +
                       ((rC & 15) | ((j & 3) << 4))) * 8) + qC;
    hfhi[(size_t)wb * 131072 + hoff] = hh;
    hflo[(size_t)wb * 131072 + hoff] = (h16)((hn - (float)hh) * 4096.f);
    out[((size_t)(n0 + rC) * 128 + t) * 512 + colC] = hn;   // fp32 output

    // partial scores for t+1: ps[p] = sum_{q} hn(n, j*8+q) * A[n][j*8+q][p]
    float Areg[16];
    const f32x4* A4 = (const f32x4*)(Af + ((size_t)(n0 + rC) * 512 + colC) * 16);
#pragma unroll
    for (int q4 = 0; q4 < 4; ++q4) {
      f32x4 v = A4[q4];
#pragma unroll
      for (int e = 0; e < 4; ++e) Areg[q4 * 4 + e] = v[e];
    }
    float ps[16];
#pragma unroll
    for (int p = 0; p < 16; ++p) ps[p] = hn * Areg[p];
#pragma unroll
    for (int m = 1; m <= 4; m <<= 1)
#pragma unroll
      for (int p = 0; p < 16; ++p) ps[p] += __shfl_xor(ps[p], m);
    if (qC == 0) {
      float* o = sbW + ((size_t)(n0 + rC) * 64 + j) * 16;
#pragma unroll
      for (int p = 0; p < 16; ++p) o[p] = ps[p];
    }
  }
}

// ---------------- Host launcher ----------------

extern "C" void kernel_launch(void* const* d_in, const int* in_sizes, int n_in,
                              void* d_out, int out_size, void* d_ws, size_t ws_size,
                              hipStream_t stream) {
  (void)in_sizes; (void)n_in; (void)out_size;
  const float* x   = (const float*)d_in[0];   // (256,128,512)
  const float* Af  = (const float*)d_in[1];   // (256,512,16)
  const float* Wx  = (const float*)d_in[2];   // (512,2048)
  const float* Wh  = (const float*)d_in[3];   // (512,2048)
  const float* Wat = (const float*)d_in[4];   // (512,2048)
  const float* bv  = (const float*)d_in[5];   // (2048,)
  float* out = (float*)d_out;                 // fp32 output (reference dtype)

  char* ws = (char*)d_ws;
  size_t off = 0;
  auto alloc = [&](size_t nb) {
    char* p = ws + off; off = (off + nb + 255) & ~(size_t)255; return p;
  };
  h16*   WhiS = (h16*)alloc(2097152ull * 2);
  h16*   WloS = (h16*)alloc(2097152ull * 2);
  float* Mws  = (float*)alloc(8388608ull * 4);     // M2[n][col][p] fp32, 33.5 MB
  float* sb   = (float*)alloc(2ull * 262144 * 4);  // score partials [2][n][j][p]
  h16*   hfhi = (h16*)alloc(262144ull * 2);        // h fragments, 2 time-bufs
  h16*   hflo = (h16*)alloc(262144ull * 2);
  float* cst  = (float*)alloc(131072ull * 4);
  size_t base_end = off;
  h16* xfhi = (h16*)alloc(16777216ull * 2);
  h16* xflo = (h16*)alloc(16777216ull * 2);
  bool xpre = (ws_size >= base_end + 2ull * 16777216ull * 2 + 4096);

  // k_m frag packs live INSIDE the xfhi/xflo region (12 MB < 64 MB): they are
  // consumed by k_m before k_xsplit overwrites the region (same stream, ordered).
  h16* afhi  = xfhi;                    // 4 MB (2M h16)
  h16* aflo  = xfhi + 2097152;          // 4 MB
  h16* wathi = xfhi + 2ull * 2097152;   // 2 MB (1M h16)
  h16* watlo = xfhi + 3ull * 2097152;   // 2 MB

  k_pack_w<<<8192, 256, 0, stream>>>(Wx, Wh, WhiS, WloS);
  k_af_pack<<<8192, 256, 0, stream>>>(Af, afhi, aflo);
  k_wat_pack<<<4096, 256, 0, stream>>>(Wat, wathi, watlo);
  k_m<<<dim3(32, 32), 256, 0, stream>>>(afhi, aflo, wathi, watlo, Mws);
  k_init<<<256, 512, 0, stream>>>(Af, hfhi, hflo, cst, sb);
  if (xpre) k_xsplit<<<8192, 256, 0, stream>>>(x, xfhi, xflo);

  for (int t = 0; t < 128; ++t) {
    const float* sbR = sb + (size_t)(t & 1) * 262144;
    float* sbW = (float*)sb + (size_t)((t + 1) & 1) * 262144;
    if (xpre)
      k_step<true><<<512, 512, 0, stream>>>(bv, Af, x, xfhi, xflo, WhiS, WloS, Mws,
                                            sbR, sbW, hfhi, hflo, cst, out, t);
    else
      k_step<false><<<512, 512, 0, stream>>>(bv, Af, x, xfhi, xflo, WhiS, WloS, Mws,
                                             sbR, sbW, hfhi, hflo, cst, out, t);
  }
}

// Round 24
// 2226.777 us; speedup vs baseline: 1.1537x; 1.1537x over previous
//
#include <hip/hip_runtime.h>
#include <math.h>

typedef unsigned short u16;
typedef _Float16 h16;
typedef _Float16 f16x8 __attribute__((ext_vector_type(8)));
typedef float f32x4 __attribute__((ext_vector_type(4)));

__device__ __forceinline__ float sigm(float x) { return 1.f / (1.f + expf(-x)); }

// ---------------- Prologue kernels ----------------

// Pack W = [Wx;Wh] (1024 x 2048 f32) into per-colblock f16 hi/lo MFMA b-frag
// streams. Layout: [j 0..64)[ks 0..32)[cf 0..2)[l 0..64)[e 0..8)
// element = W[k = ks*32 + (l>>4)*8 + e][acol], acol = (c32>>3)*512 + j*8 + (c32&7),
// c32 = cf*16 + (l&15).  lo scaled by 2^12 (exact) to stay in fp16 normal range.
__global__ void k_pack_w(const float* __restrict__ Wx, const float* __restrict__ Wh,
                         h16* __restrict__ WhiS, h16* __restrict__ WloS) {
  unsigned idx = blockIdx.x * 256 + threadIdx.x;   // 0..2097151
  unsigned e = idx & 7, l = (idx >> 3) & 63, cf = (idx >> 9) & 1;
  unsigned t2 = idx >> 10;                          // j*32 + ks
  unsigned j = t2 >> 5, ks = t2 & 31;
  unsigned k = ks * 32 + ((l >> 4) << 3) + e;       // 0..1023
  unsigned c32 = cf * 16 + (l & 15);
  unsigned acol = (c32 >> 3) * 512 + j * 8 + (c32 & 7);
  float v = (k < 512) ? Wx[(size_t)k * 2048 + acol]
                      : Wh[(size_t)(k - 512) * 2048 + acol];
  h16 hi = (h16)v;
  WhiS[idx] = hi;
  WloS[idx] = (h16)((v - (float)hi) * 4096.f);
}

// Af -> a-frag hi/lo streams for k_m: [n][ksg 16][l 64][e 8],
// element = A[n][k = ksg*32+(l>>4)*8+e][p = l&15].
__global__ void k_af_pack(const float* __restrict__ Af, h16* __restrict__ afhi,
                          h16* __restrict__ aflo) {
  unsigned idx = blockIdx.x * 256 + threadIdx.x;   // 0..2097151
  unsigned e = idx & 7, l = (idx >> 3) & 63, ksg = (idx >> 9) & 15, n = idx >> 13;
  unsigned k = ksg * 32 + ((l >> 4) << 3) + e;
  float v = Af[(size_t)n * 8192 + k * 16 + (l & 15)];
  h16 hi = (h16)v;
  afhi[idx] = hi;
  aflo[idx] = (h16)((v - (float)hi) * 4096.f);
}

// Wattn -> b-frag hi/lo streams for k_m: [cg 128][ksg 16][l 64][e 8],
// element = Wat[k = ksg*32+(l>>4)*8+e][col = cg*16 + (l&15)].
__global__ void k_wat_pack(const float* __restrict__ Wat, h16* __restrict__ wathi,
                           h16* __restrict__ watlo) {
  unsigned idx = blockIdx.x * 256 + threadIdx.x;   // 0..1048575
  unsigned e = idx & 7, l = (idx >> 3) & 63, ksg = (idx >> 9) & 15, cg = idx >> 13;
  unsigned k = ksg * 32 + ((l >> 4) << 3) + e;
  float v = Wat[(size_t)k * 2048 + cg * 16 + (l & 15)];
  h16 hi = (h16)v;
  wathi[idx] = hi;
  watlo[idx] = (h16)((v - (float)hi) * 4096.f);
}

// M2[n][col][p] = sum_k A[n][k][p]*Wat[k][col], f16 hi/lo 3-pass MFMA from
// prepacked frag streams. Grid (32 ct, 32 ng) x 256 thr: block = 64 cols x 8 n.
// acc2 split into two accumulators (a/b) to break the per-i serial MFMA chain
// (R21: 83 -> 51 us, 1.4 TB/s).
__global__ __launch_bounds__(256) void k_m(const h16* __restrict__ afhi,
                                           const h16* __restrict__ aflo,
                                           const h16* __restrict__ wathi,
                                           const h16* __restrict__ watlo,
                                           float* __restrict__ M2) {
  const int tid = threadIdx.x;
  const int ct = blockIdx.x, ng = blockIdx.y;
  const int l = tid & 63, w = tid >> 6;
  const int cg = ct * 4 + w;
  const int col = cg * 16 + (l & 15);
  const int lq = l >> 4;
  f32x4 acc1[8], acc2a[8], acc2b[8];
#pragma unroll
  for (int i = 0; i < 8; ++i) {
    acc1[i] = (f32x4){0.f, 0.f, 0.f, 0.f};
    acc2a[i] = (f32x4){0.f, 0.f, 0.f, 0.f};
    acc2b[i] = (f32x4){0.f, 0.f, 0.f, 0.f};
  }
  for (int ksg = 0; ksg < 16; ++ksg) {
    const size_t boff = (((size_t)cg * 16 + ksg) * 64 + l) * 8;
    const f16x8 bh = *(const f16x8*)(wathi + boff);
    const f16x8 bl = *(const f16x8*)(watlo + boff);
#pragma unroll
    for (int i = 0; i < 8; ++i) {
      const size_t aoff = (((size_t)(ng * 8 + i) * 16 + ksg) * 64 + l) * 8;
      const f16x8 ah = *(const f16x8*)(afhi + aoff);
      const f16x8 al = *(const f16x8*)(aflo + aoff);
      acc1[i]  = __builtin_amdgcn_mfma_f32_16x16x32_f16(ah, bh, acc1[i], 0, 0, 0);
      acc2a[i] = __builtin_amdgcn_mfma_f32_16x16x32_f16(al, bh, acc2a[i], 0, 0, 0);
      acc2b[i] = __builtin_amdgcn_mfma_f32_16x16x32_f16(ah, bl, acc2b[i], 0, 0, 0);
    }
  }
#pragma unroll
  for (int i = 0; i < 8; ++i) {
    float4 o;
    o.x = acc1[i][0] + (acc2a[i][0] + acc2b[i][0]) * (1.f / 4096.f);
    o.y = acc1[i][1] + (acc2a[i][1] + acc2b[i][1]) * (1.f / 4096.f);
    o.z = acc1[i][2] + (acc2a[i][2] + acc2b[i][2]) * (1.f / 4096.f);
    o.w = acc1[i][3] + (acc2a[i][3] + acc2b[i][3]) * (1.f / 4096.f);
    *(float4*)(M2 + ((size_t)(ng * 8 + i) * 2048 + col) * 16 + lq * 4) = o;
  }
}

// x (f32) -> xfhi/xflo in MFMA-FRAGMENT order: [t][g 8][ksg 16][rt 2][l][e],
// element = x[n = g*32+rt*16+(l&15)][t][k = ksg*32+(l>>4)*8+e].
__global__ void k_xsplit(const float* __restrict__ x, h16* __restrict__ xfhi,
                         h16* __restrict__ xflo) {
  unsigned tg = blockIdx.x * 256 + threadIdx.x;   // 0..2097151
  unsigned l = tg & 63, rt = (tg >> 6) & 1, ksg = (tg >> 7) & 15;
  unsigned g = (tg >> 11) & 7, t = tg >> 14;
  int n = g * 32 + rt * 16 + (l & 15);
  int k0 = ksg * 32 + (l >> 4) * 8;
  const float* xp = x + ((size_t)n * 128 + t) * 512 + k0;
  f32x4 v0 = *(const f32x4*)xp, v1 = *(const f32x4*)(xp + 4);
  float vv[8] = {v0[0], v0[1], v0[2], v0[3], v1[0], v1[1], v1[2], v1[3]};
  union { h16 h[8]; uint4 u; } a, b;
#pragma unroll
  for (int e = 0; e < 8; ++e) {
    h16 hh = (h16)vv[e];
    a.h[e] = hh;
    b.h[e] = (h16)((vv[e] - (float)hh) * 4096.f);
  }
  *(uint4*)(xfhi + (size_t)tg * 8) = a.u;
  *(uint4*)(xflo + (size_t)tg * 8) = b.u;
}

// h0 = c0 = mean_p A[n][k][p]; seeds cst, h-FRAGMENT buffers (buf 0) and the
// step-0 score partials sb0[n][j][p]. 256 blocks (n) x 512 threads (k).
// h-frag addr: [g][hksg=k>>5][rt=(n>>4)&1][lfrag=(n&15)|(((k>>3)&3)<<4)][e=k&7]
__global__ __launch_bounds__(512) void k_init(const float* __restrict__ Af,
                                              h16* __restrict__ hfhi,
                                              h16* __restrict__ hflo,
                                              float* __restrict__ cst,
                                              float* __restrict__ sb0) {
  const int n = blockIdx.x, k = threadIdx.x;
  float Areg[16];
  const f32x4* A4 = (const f32x4*)(Af + (size_t)n * 8192 + k * 16);
#pragma unroll
  for (int q4 = 0; q4 < 4; ++q4) {
    f32x4 v = A4[q4];
#pragma unroll
    for (int e = 0; e < 4; ++e) Areg[q4 * 4 + e] = v[e];
  }
  float s = 0.f;
#pragma unroll
  for (int p = 0; p < 16; ++p) s += Areg[p];
  s *= 0.0625f;
  cst[n * 512 + k] = s;
  h16 hh = (h16)s;
  const int g = n >> 5;
  const int hoff = ((((g * 16 + (k >> 5)) * 2 + ((n >> 4) & 1)) * 64 +
                     ((n & 15) | (((k >> 3) & 3) << 4))) * 8) + (k & 7);
  hfhi[hoff] = hh;
  hflo[hoff] = (h16)((s - (float)hh) * 4096.f);
  float ps[16];
#pragma unroll
  for (int p = 0; p < 16; ++p) ps[p] = s * Areg[p];
#pragma unroll
  for (int m = 1; m <= 4; m <<= 1)
#pragma unroll
    for (int p = 0; p < 16; ++p) ps[p] += __shfl_xor(ps[p], m);
  if ((k & 7) == 0) {
    float* o = sb0 + ((size_t)n * 64 + (k >> 3)) * 16;
#pragma unroll
    for (int p = 0; p < 16; ++p) o[p] = ps[p];
  }
}

// ------------- Fused per-step kernel: softmax + GEMM + cell + next-scores -----
// 512 blocks x 512 threads, 2 blocks/CU (traffic-optimal RG=8 tiling; R19/R23
// measured both occupancy directions worse). Block: g = bid>>6 (rows n0=g*32),
// j = (bid&7)*8 + ((bid>>3)&7) (XCD-pinned W slice). Measured-best k_step.
template<bool XPRE>
__global__ __launch_bounds__(512, 4) void k_step(
    const float* __restrict__ bv, const float* __restrict__ Af,
    const float* __restrict__ x, const h16* __restrict__ xfhi, const h16* __restrict__ xflo,
    const h16* __restrict__ WhiS, const h16* __restrict__ WloS,
    const float* __restrict__ Mws,
    const float* __restrict__ sbR, float* __restrict__ sbW,
    h16* __restrict__ hfhi, h16* __restrict__ hflo,
    float* __restrict__ cst, float* __restrict__ out, int t) {
  __shared__ float P[7 * 1056];   // 7 slots of [32 rows][33] : 29568 B
  __shared__ float wsh[32][17];   // softmax weights for this row group (+1 pad)

  const int tid = threadIdx.x;
  const int l = tid & 63, wv = tid >> 6;
  const int bid = blockIdx.x;
  const int g = bid >> 6;                          // 0..7
  const int j = (bid & 7) * 8 + ((bid >> 3) & 7);  // 0..63
  const int n0 = g * 32;

  // ---- [S] softmax: s[n][p] = sum_j sbR[n][j][p]; w = softmax(s/sqrt(512)) ----
  {
    const int nS = tid >> 4, pS = tid & 15;
    const float* sr = sbR + ((size_t)(n0 + nS) * 64) * 16 + pS;
    float s = 0.f;
#pragma unroll 8
    for (int jj = 0; jj < 64; ++jj) s += sr[jj * 16];
    s *= 0.04419417382415922f;   // 1/sqrt(512)
    float m = s;
#pragma unroll
    for (int o = 8; o >= 1; o >>= 1) m = fmaxf(m, __shfl_xor(m, o, 16));
    float e = __expf(s - m);
    float se = e;
#pragma unroll
    for (int o = 8; o >= 1; o >>= 1) se += __shfl_xor(se, o, 16);
    wsh[nS][pS] = e / se;   // ordered before cell use by the tree's syncthreads
  }

  const h16* whiJ = WhiS + (size_t)j * 32768;
  const h16* wloJ = WloS + (size_t)j * 32768;

  const int rC = tid >> 3, qC = tid & 7;   // cell mapping (tid < 256 only)
  const int colC = j * 8 + qC;
  const float b_i = bv[colC], b_f = bv[512 + colC], b_o = bv[1024 + colC],
              b_g = bv[1536 + colC];

  const int rb = t & 1, wb = rb ^ 1;
  const h16* hfhiR = hfhi + (size_t)rb * 131072;
  const h16* hfloR = hflo + (size_t)rb * 131072;

  f32x4 acc1[2][2], acc2[2][2];
#pragma unroll
  for (int rt = 0; rt < 2; ++rt)
#pragma unroll
    for (int cf = 0; cf < 2; ++cf) {
      acc1[rt][cf] = (f32x4){0.f, 0.f, 0.f, 0.f};
      acc2[rt][cf] = (f32x4){0.f, 0.f, 0.f, 0.f};
    }

  auto kstep = [&](int ksg) {
    const f16x8 bh0 = *(const f16x8*)(whiJ + ((size_t)(ksg * 2 + 0) * 64 + l) * 8);
    const f16x8 bh1 = *(const f16x8*)(whiJ + ((size_t)(ksg * 2 + 1) * 64 + l) * 8);
    const f16x8 bl0 = *(const f16x8*)(wloJ + ((size_t)(ksg * 2 + 0) * 64 + l) * 8);
    const f16x8 bl1 = *(const f16x8*)(wloJ + ((size_t)(ksg * 2 + 1) * 64 + l) * 8);
    f16x8 Ah[2], Al[2];
    if (ksg < 16) {
      if (XPRE) {
#pragma unroll
        for (int rt = 0; rt < 2; ++rt) {
          const size_t base = ((((size_t)t * 8 + g) * 16 + ksg) * 2 + rt) * 512 + l * 8;
          Ah[rt] = *(const f16x8*)(xfhi + base);
          Al[rt] = *(const f16x8*)(xflo + base);
        }
      } else {
#pragma unroll
        for (int rt = 0; rt < 2; ++rt) {
          const int n_x = g * 32 + rt * 16 + (l & 15);
          const int k_x = ksg * 32 + (l >> 4) * 8;
          const float* xp = x + ((size_t)n_x * 128 + t) * 512 + k_x;
          f32x4 v0 = *(const f32x4*)xp, v1 = *(const f32x4*)(xp + 4);
          float vv[8] = {v0[0], v0[1], v0[2], v0[3], v1[0], v1[1], v1[2], v1[3]};
#pragma unroll
          for (int e = 0; e < 8; ++e) {
            h16 hh = (h16)vv[e];
            Ah[rt][e] = hh;
            Al[rt][e] = (h16)((vv[e] - (float)hh) * 4096.f);
          }
        }
      }
    } else {
#pragma unroll
      for (int rt = 0; rt < 2; ++rt) {
        const size_t base = (((size_t)(g * 16 + (ksg - 16)) * 2 + rt) * 64 + l) * 8;
        Ah[rt] = *(const f16x8*)(hfhiR + base);
        Al[rt] = *(const f16x8*)(hfloR + base);
      }
    }
#pragma unroll
    for (int rt = 0; rt < 2; ++rt) {
      acc1[rt][0] = __builtin_amdgcn_mfma_f32_16x16x32_f16(Ah[rt], bh0, acc1[rt][0], 0, 0, 0);
      acc1[rt][1] = __builtin_amdgcn_mfma_f32_16x16x32_f16(Ah[rt], bh1, acc1[rt][1], 0, 0, 0);
      acc2[rt][0] = __builtin_amdgcn_mfma_f32_16x16x32_f16(Al[rt], bh0, acc2[rt][0], 0, 0, 0);
      acc2[rt][1] = __builtin_amdgcn_mfma_f32_16x16x32_f16(Al[rt], bh1, acc2[rt][1], 0, 0, 0);
      acc2[rt][0] = __builtin_amdgcn_mfma_f32_16x16x32_f16(Ah[rt], bl0, acc2[rt][0], 0, 0, 0);
      acc2[rt][1] = __builtin_amdgcn_mfma_f32_16x16x32_f16(Ah[rt], bl1, acc2[rt][1], 0, 0, 0);
    }
  };

  // ---- [G] K coverage: ksg = wv + 8i, i = 0..3 (x: 0..15, h: 16..31) ----
#pragma unroll
  for (int i = 0; i < 4; ++i) kstep(wv + 8 * i);

  // combine hi + 2^-12 * lo-cross
  float accf[2][2][4];
#pragma unroll
  for (int rt = 0; rt < 2; ++rt)
#pragma unroll
    for (int cf = 0; cf < 2; ++cf)
#pragma unroll
      for (int rg = 0; rg < 4; ++rg)
        accf[rt][cf][rg] = acc1[rt][cf][rg] + acc2[rt][cf][rg] * (1.f / 4096.f);

  auto publish = [&](int slot) {
#pragma unroll
    for (int rt = 0; rt < 2; ++rt)
#pragma unroll
      for (int cf = 0; cf < 2; ++cf)
#pragma unroll
        for (int rg = 0; rg < 4; ++rg)
          P[slot * 1056 + (rt * 16 + (l >> 4) * 4 + rg) * 33 + cf * 16 + (l & 15)] =
              accf[rt][cf][rg];
  };
  auto addin = [&](int slot) {
#pragma unroll
    for (int rt = 0; rt < 2; ++rt)
#pragma unroll
      for (int cf = 0; cf < 2; ++cf)
#pragma unroll
        for (int rg = 0; rg < 4; ++rg)
          accf[rt][cf][rg] +=
              P[slot * 1056 + (rt * 16 + (l >> 4) * 4 + rg) * 33 + cf * 16 + (l & 15)];
  };

  // 8-wave reduction tree: 8 -> 4 -> 2 -> 1 copies, then final publish to slot 0
  if (wv >= 4) publish(wv - 4);
  __syncthreads();
  if (wv < 4) addin(wv);
  if (wv == 2) publish(4);
  if (wv == 3) publish(5);
  __syncthreads();
  if (wv == 0) addin(4);
  if (wv == 1) { addin(5); publish(6); }
  __syncthreads();
  if (wv == 0) { addin(6); publish(0); }
  __syncthreads();

  // ---- [C] gates + w@M + state update + next-step score partials ----
  if (tid < 256) {
    const float* Mr = Mws + ((size_t)(n0 + rC) * 2048 + colC) * 16;
    float am[4];
#pragma unroll
    for (int f = 0; f < 4; ++f) {
      const float* mp = Mr + (size_t)f * 8192;   // gate offset: 512 cols * 16 p
      float s = 0.f;
#pragma unroll
      for (int p = 0; p < 16; ++p) s += wsh[rC][p] * mp[p];
      am[f] = s;
    }
    float ai = P[rC * 33 + qC] + am[0] + b_i;
    float af_ = P[rC * 33 + 8 + qC] + am[1] + b_f;
    float ao = P[rC * 33 + 16 + qC] + am[2] + b_o;
    float ag = P[rC * 33 + 24 + qC] + am[3] + b_g;
    float ig = sigm(ai), fg = sigm(af_), og = sigm(ao), gg = tanhf(ag);
    const size_t cix = (size_t)(n0 + rC) * 512 + colC;
    float c = cst[cix];
    float cn = fg * c + ig * gg;
    cst[cix] = cn;
    float hn = og * tanhf(cn);
    h16 hh = (h16)hn;
    // h-fragment write: k_h = colC; hksg = j>>2, lq = j&3, e = qC
    const int hoff = ((((g * 16 + (j >> 2)) * 2 + (rC >> 4)) * 64 +
                       ((rC & 15) | ((j & 3) << 4))) * 8) + qC;
    hfhi[(size_t)wb * 131072 + hoff] = hh;
    hflo[(size_t)wb * 131072 + hoff] = (h16)((hn - (float)hh) * 4096.f);
    out[((size_t)(n0 + rC) * 128 + t) * 512 + colC] = hn;   // fp32 output

    // partial scores for t+1: ps[p] = sum_{q} hn(n, j*8+q) * A[n][j*8+q][p]
    float Areg[16];
    const f32x4* A4 = (const f32x4*)(Af + ((size_t)(n0 + rC) * 512 + colC) * 16);
#pragma unroll
    for (int q4 = 0; q4 < 4; ++q4) {
      f32x4 v = A4[q4];
#pragma unroll
      for (int e = 0; e < 4; ++e) Areg[q4 * 4 + e] = v[e];
    }
    float ps[16];
#pragma unroll
    for (int p = 0; p < 16; ++p) ps[p] = hn * Areg[p];
#pragma unroll
    for (int m = 1; m <= 4; m <<= 1)
#pragma unroll
      for (int p = 0; p < 16; ++p) ps[p] += __shfl_xor(ps[p], m);
    if (qC == 0) {
      float* o = sbW + ((size_t)(n0 + rC) * 64 + j) * 16;
#pragma unroll
      for (int p = 0; p < 16; ++p) o[p] = ps[p];
    }
  }
}

// ---------------- Host launcher ----------------

extern "C" void kernel_launch(void* const* d_in, const int* in_sizes, int n_in,
                              void* d_out, int out_size, void* d_ws, size_t ws_size,
                              hipStream_t stream) {
  (void)in_sizes; (void)n_in; (void)out_size;
  const float* x   = (const float*)d_in[0];   // (256,128,512)
  const float* Af  = (const float*)d_in[1];   // (256,512,16)
  const float* Wx  = (const float*)d_in[2];   // (512,2048)
  const float* Wh  = (const float*)d_in[3];   // (512,2048)
  const float* Wat = (const float*)d_in[4];   // (512,2048)
  const float* bv  = (const float*)d_in[5];   // (2048,)
  float* out = (float*)d_out;                 // fp32 output (reference dtype)

  char* ws = (char*)d_ws;
  size_t off = 0;
  auto alloc = [&](size_t nb) {
    char* p = ws + off; off = (off + nb + 255) & ~(size_t)255; return p;
  };
  h16*   WhiS = (h16*)alloc(2097152ull * 2);
  h16*   WloS = (h16*)alloc(2097152ull * 2);
  float* Mws  = (float*)alloc(8388608ull * 4);     // M2[n][col][p] fp32, 33.5 MB
  float* sb   = (float*)alloc(2ull * 262144 * 4);  // score partials [2][n][j][p]
  h16*   hfhi = (h16*)alloc(262144ull * 2);        // h fragments, 2 time-bufs
  h16*   hflo = (h16*)alloc(262144ull * 2);
  float* cst  = (float*)alloc(131072ull * 4);
  size_t base_end = off;
  h16* xfhi = (h16*)alloc(16777216ull * 2);
  h16* xflo = (h16*)alloc(16777216ull * 2);
  bool xpre = (ws_size >= base_end + 2ull * 16777216ull * 2 + 4096);

  // k_m frag packs live INSIDE the xfhi/xflo region (12 MB < 64 MB): they are
  // consumed by k_m before k_xsplit overwrites the region (same stream, ordered).
  h16* afhi  = xfhi;                    // 4 MB (2M h16)
  h16* aflo  = xfhi + 2097152;          // 4 MB
  h16* wathi = xfhi + 2ull * 2097152;   // 2 MB (1M h16)
  h16* watlo = xfhi + 3ull * 2097152;   // 2 MB

  k_pack_w<<<8192, 256, 0, stream>>>(Wx, Wh, WhiS, WloS);
  k_af_pack<<<8192, 256, 0, stream>>>(Af, afhi, aflo);
  k_wat_pack<<<4096, 256, 0, stream>>>(Wat, wathi, watlo);
  k_m<<<dim3(32, 32), 256, 0, stream>>>(afhi, aflo, wathi, watlo, Mws);
  k_init<<<256, 512, 0, stream>>>(Af, hfhi, hflo, cst, sb);
  if (xpre) k_xsplit<<<8192, 256, 0, stream>>>(x, xfhi, xflo);

  for (int t = 0; t < 128; ++t) {
    const float* sbR = sb + (size_t)(t & 1) * 262144;
    float* sbW = (float*)sb + (size_t)((t + 1) & 1) * 262144;
    if (xpre)
      k_step<true><<<512, 512, 0, stream>>>(bv, Af, x, xfhi, xflo, WhiS, WloS, Mws,
                                            sbR, sbW, hfhi, hflo, cst, out, t);
    else
      k_step<false><<<512, 512, 0, stream>>>(bv, Af, x, xfhi, xflo, WhiS, WloS, Mws,
                                             sbR, sbW, hfhi, hflo, cst, out, t);
  }
}